// Round 2
// baseline (971.480 us; speedup 1.0000x reference)
//
#include <hip/hip_runtime.h>

#define N_PTS   30000
#define M_ATOMS 8000
#define M_PAD   8064          // padded to multiple of 64
#define D       16
#define KNN     16
#define EPS     1e-5f
#define SLOPE   0.2f
#define BN_COUNT 480000.0f    // N_PTS * KNN

__device__ __forceinline__ float leaky(float x) { return x > 0.f ? x : SLOPE * x; }

// ---------------------------------------------------------------------------
// K1: pack atoms as (x,y,z,|y|^2) float4 (padded with sentinel), and run the
// 3-layer transform_types MLP -> t[M,16]
// ---------------------------------------------------------------------------
#define LAYER(IN, OUT, W, B)                                        \
  _Pragma("unroll") for (int j = 0; j < 16; ++j) {                  \
    float acc = B[j];                                               \
    _Pragma("unroll") for (int i = 0; i < 16; ++i)                  \
      acc = fmaf(IN[i], W[i*16+j], acc);                            \
    OUT[j] = leaky(acc);                                            \
  }

__global__ void __launch_bounds__(256) k1_prep(
    const float* __restrict__ atom_xyz, const float* __restrict__ atom_types,
    const float* __restrict__ Wt1, const float* __restrict__ bt1,
    const float* __restrict__ Wt2, const float* __restrict__ bt2,
    const float* __restrict__ Wt3, const float* __restrict__ bt3,
    float4* __restrict__ atoms4, float* __restrict__ t_out) {
  __shared__ float w1[256], w2[256], w3[256], bb1[16], bb2[16], bb3[16];
  int tid = threadIdx.x;
  w1[tid] = Wt1[tid]; w2[tid] = Wt2[tid]; w3[tid] = Wt3[tid];
  if (tid < 16) { bb1[tid] = bt1[tid]; bb2[tid] = bt2[tid]; bb3[tid] = bt3[tid]; }
  __syncthreads();
  int m = blockIdx.x * 256 + tid;
  if (m >= M_PAD) return;
  if (m >= M_ATOMS) {                       // sentinel: d2 = x2 + 1e30, never selected
    atoms4[m] = make_float4(0.f, 0.f, 0.f, 1e30f);
    return;
  }
  float ax = atom_xyz[m*3+0], ay = atom_xyz[m*3+1], az = atom_xyz[m*3+2];
  atoms4[m] = make_float4(ax, ay, az, fmaf(ax,ax, fmaf(ay,ay, az*az)));

  float u[16], v[16];
  const float4* tp = (const float4*)(atom_types + (size_t)m*16);
  float4 q0 = tp[0], q1 = tp[1], q2 = tp[2], q3 = tp[3];
  u[0]=q0.x; u[1]=q0.y; u[2]=q0.z; u[3]=q0.w;
  u[4]=q1.x; u[5]=q1.y; u[6]=q1.z; u[7]=q1.w;
  u[8]=q2.x; u[9]=q2.y; u[10]=q2.z; u[11]=q2.w;
  u[12]=q3.x; u[13]=q3.y; u[14]=q3.z; u[15]=q3.w;

  LAYER(u, v, w1, bb1);
  LAYER(v, u, w2, bb2);
  LAYER(u, v, w3, bb3);

  float4* op = (float4*)(t_out + (size_t)m*16);
  op[0] = make_float4(v[0], v[1], v[2], v[3]);
  op[1] = make_float4(v[4], v[5], v[6], v[7]);
  op[2] = make_float4(v[8], v[9], v[10], v[11]);
  op[3] = make_float4(v[12], v[13], v[14], v[15]);
}

// ---------------------------------------------------------------------------
// K2: exact 16-NN per point. One wave per point; sorted top-16 lives in
// lanes 0..15 (ascending d2, ties keep lower atom index = matches lax.top_k).
// ---------------------------------------------------------------------------
__global__ void __launch_bounds__(256) k2_knn(
    const float* __restrict__ xyz, const float4* __restrict__ atoms4,
    int* __restrict__ knn_idx, float* __restrict__ knn_invd) {
  int lane = threadIdx.x & 63;
  int n = blockIdx.x * 4 + (threadIdx.x >> 6);
  if (n >= N_PTS) return;                    // wave-uniform

  float px = xyz[n*3+0], py = xyz[n*3+1], pz = xyz[n*3+2];
  float x2 = fmaf(px,px, fmaf(py,py, pz*pz));

  float lv = 3.4e38f;   // this lane's slot value (lanes 0..15 = sorted list)
  int   li = 0;
  float thresh = 3.4e38f;  // current 16th-best (wave-uniform)

  for (int base = 0; base < M_PAD; base += 64) {
    float4 a = atoms4[base + lane];
    float dotp = fmaf(px,a.x, fmaf(py,a.y, pz*a.z));
    float d2 = (x2 + a.w) - 2.f*dotp;        // same expansion as reference
    unsigned long long mask = __ballot(d2 < thresh);
    while (mask) {
      int src = __ffsll(mask) - 1;
      mask &= mask - 1;
      float dc = __shfl(d2, src, 64);        // uniform broadcast
      if (dc < thresh) {                     // re-check against tightened thresh
        int mc = base + src;
        bool ins = (lane < KNN) && (dc < lv);   // strict: ties keep earlier (lower idx)
        float pv = __shfl_up(lv, 1, 64);
        int   pi = __shfl_up(li, 1, 64);
        int   pins = __shfl_up((int)ins, 1, 64);
        if (lane == 0) pins = 0;
        if (ins) {
          lv = pins ? pv : dc;
          li = pins ? pi : mc;
        }
        thresh = __shfl(lv, KNN-1, 64);
      }
    }
  }

  if (lane < KNN) {
    float4 a = atoms4[li];
    float dx = px - a.x, dy = py - a.y, dz = pz - a.z;
    float dd = fmaf(dx,dx, fmaf(dy,dy, dz*dz));   // exact recompute (reference)
    knn_idx [n*KNN + lane] = li;
    knn_invd[n*KNN + lane] = 1.f / dd;
  }
}

// ---------------------------------------------------------------------------
// conv1 (feat[17] @ W1[17,16] + b1) + leaky, weights in LDS
// ---------------------------------------------------------------------------
__device__ __forceinline__ void conv1_leaky(const float* tr, float iv,
                                            const float* w, const float* b,
                                            float* a) {
#pragma unroll
  for (int j = 0; j < 16; ++j) {
    float acc = fmaf(iv, w[256+j], b[j]);
#pragma unroll
    for (int i = 0; i < 16; ++i) acc = fmaf(tr[i], w[i*16+j], acc);
    a[j] = leaky(acc);
  }
}

__device__ __forceinline__ void load_trow(const float* __restrict__ t_in,
                                          int idx, float* tr) {
  const float4* tp = (const float4*)(t_in + (size_t)idx*16);
  float4 q0 = tp[0], q1 = tp[1], q2 = tp[2], q3 = tp[3];
  tr[0]=q0.x; tr[1]=q0.y; tr[2]=q0.z; tr[3]=q0.w;
  tr[4]=q1.x; tr[5]=q1.y; tr[6]=q1.z; tr[7]=q1.w;
  tr[8]=q2.x; tr[9]=q2.y; tr[10]=q2.z; tr[11]=q2.w;
  tr[12]=q3.x; tr[13]=q3.y; tr[14]=q3.z; tr[15]=q3.w;
}

// ---------------------------------------------------------------------------
// K3: BN1 statistics (sum / sumsq of a1 = leaky(conv1(feat)) per channel)
// gstats layout: [sum1(16) | sq1(16) | sum2(16) | sq2(16)]
// ---------------------------------------------------------------------------
__global__ void __launch_bounds__(256) k3_stats1(
    const int* __restrict__ knn_idx, const float* __restrict__ knn_invd,
    const float* __restrict__ t_in,
    const float* __restrict__ W1, const float* __restrict__ b1,
    float* __restrict__ gstats) {
  __shared__ float w[272], b[16], acc[32];
  int tid = threadIdx.x;
  w[tid] = W1[tid];
  if (tid < 16) w[256+tid] = W1[256+tid];    // FIX: tail row (inv_d weights)
  if (tid < 16)  b[tid] = b1[tid];
  if (tid < 32)  acc[tid] = 0.f;
  __syncthreads();

  int g = blockIdx.x * 256 + tid;            // 1875*256 == 480000 exactly
  int idx = knn_idx[g];
  float iv = knn_invd[g];
  float tr[16], a[16];
  load_trow(t_in, idx, tr);
  conv1_leaky(tr, iv, w, b, a);
#pragma unroll
  for (int j = 0; j < 16; ++j) {
    atomicAdd(&acc[j],      a[j]);
    atomicAdd(&acc[16+j],   a[j]*a[j]);
  }
  __syncthreads();
  if (tid < 32) atomicAdd(&gstats[tid], acc[tid]);
}

// ---------------------------------------------------------------------------
// K4: main pass. Recompute a1, apply BN1 -> h, fx1 = sum_k h (stored),
// a2 = leaky(h@W2+b2), s2 = sum_k a2 (stored), accumulate BN2 stats.
// Block = 16 points x 16 neighbors.
// ---------------------------------------------------------------------------
__global__ void __launch_bounds__(256) k4_main(
    const int* __restrict__ knn_idx, const float* __restrict__ knn_invd,
    const float* __restrict__ t_in,
    const float* __restrict__ W1, const float* __restrict__ b1,
    const float* __restrict__ W2, const float* __restrict__ b2,
    const float* __restrict__ g1, const float* __restrict__ be1,
    float* __restrict__ fx1_out, float* __restrict__ s2_out,
    float* __restrict__ gstats) {
  __shared__ float w1s[272], b1s[16], w2s[256], b2s[16];
  __shared__ float sc1[16], sh1[16];
  __shared__ float buf[16*16*17];            // [p][k][j] padded to 17
  __shared__ float acc[32];
  int tid = threadIdx.x;
  w1s[tid] = W1[tid];
  if (tid < 16) w1s[256+tid] = W1[256+tid];  // FIX: tail row (inv_d weights)
  w2s[tid] = W2[tid];
  if (tid < 16) { b1s[tid] = b1[tid]; b2s[tid] = b2[tid]; }
  if (tid < 32) acc[tid] = 0.f;
  if (tid < 16) {
    float mean = gstats[tid]    * (1.f/BN_COUNT);
    float var  = gstats[16+tid] * (1.f/BN_COUNT) - mean*mean;
    float s = g1[tid] / sqrtf(var + EPS);
    sc1[tid] = s;
    sh1[tid] = be1[tid] - mean * s;
  }
  __syncthreads();

  int g = blockIdx.x * 256 + tid;
  int p = tid >> 4;                          // point slot within block
  int k = tid & 15;                          // neighbor slot
  int idx = knn_idx[g];
  float iv = knn_invd[g];
  float tr[16], a1[16], h[16], a2[16];
  load_trow(t_in, idx, tr);
  conv1_leaky(tr, iv, w1s, b1s, a1);
#pragma unroll
  for (int j = 0; j < 16; ++j) h[j] = fmaf(a1[j], sc1[j], sh1[j]);
#pragma unroll
  for (int j = 0; j < 16; ++j) {
    float accj = b2s[j];
#pragma unroll
    for (int i = 0; i < 16; ++i) accj = fmaf(h[i], w2s[i*16+j], accj);
    a2[j] = leaky(accj);
    atomicAdd(&acc[j],    a2[j]);
    atomicAdd(&acc[16+j], a2[j]*a2[j]);
  }

  float* myrow = &buf[(p*16 + k)*17];
  // ---- reduce h over k -> fx1 ----
#pragma unroll
  for (int j = 0; j < 16; ++j) myrow[j] = h[j];
  __syncthreads();
  {
    int p2 = tid >> 4, j2 = tid & 15;
    float s = 0.f;
#pragma unroll
    for (int kk = 0; kk < 16; ++kk) s += buf[(p2*16+kk)*17 + j2];
    fx1_out[(size_t)blockIdx.x*256 + tid] = s;   // == fx1[n*16+j]
  }
  __syncthreads();
  // ---- reduce a2 over k -> s2 ----
#pragma unroll
  for (int j = 0; j < 16; ++j) myrow[j] = a2[j];
  __syncthreads();
  {
    int p2 = tid >> 4, j2 = tid & 15;
    float s = 0.f;
#pragma unroll
    for (int kk = 0; kk < 16; ++kk) s += buf[(p2*16+kk)*17 + j2];
    s2_out[(size_t)blockIdx.x*256 + tid] = s;
  }
  __syncthreads();
  if (tid < 32) atomicAdd(&gstats[32 + tid], acc[tid]);
}

// ---------------------------------------------------------------------------
// K5: fx2 = scale2*s2 + 16*shift2 ; out = [fx1, fx2] @ W3 + b3
// ---------------------------------------------------------------------------
__global__ void __launch_bounds__(256) k5_final(
    const float* __restrict__ fx1_in, const float* __restrict__ s2_in,
    const float* __restrict__ gstats,
    const float* __restrict__ W3, const float* __restrict__ b3,
    const float* __restrict__ g2, const float* __restrict__ be2,
    float* __restrict__ out) {
  __shared__ float w[512], bb[16], sc2[16], sh2[16];
  int tid = threadIdx.x;
  w[tid] = W3[tid]; w[256+tid] = W3[256+tid];
  if (tid < 16) {
    bb[tid] = b3[tid];
    float mean = gstats[32+tid] * (1.f/BN_COUNT);
    float var  = gstats[48+tid] * (1.f/BN_COUNT) - mean*mean;
    float s = g2[tid] / sqrtf(var + EPS);
    sc2[tid] = s;
    sh2[tid] = be2[tid] - mean * s;
  }
  __syncthreads();
  int n = blockIdx.x * 256 + tid;
  if (n >= N_PTS) return;

  float f1[16], f2[16];
  load_trow(fx1_in, n, f1);   // same 4xfloat4 row-load pattern
  load_trow(s2_in,  n, f2);
#pragma unroll
  for (int i = 0; i < 16; ++i) f2[i] = fmaf(sc2[i], f2[i], 16.f * sh2[i]);

  float4* op = (float4*)(out + (size_t)n*16);
  float o[16];
#pragma unroll
  for (int j = 0; j < 16; ++j) {
    float accj = bb[j];
#pragma unroll
    for (int i = 0; i < 16; ++i) accj = fmaf(f1[i], w[i*16+j], accj);
#pragma unroll
    for (int i = 0; i < 16; ++i) accj = fmaf(f2[i], w[(16+i)*16+j], accj);
    o[j] = accj;
  }
  op[0] = make_float4(o[0], o[1], o[2], o[3]);
  op[1] = make_float4(o[4], o[5], o[6], o[7]);
  op[2] = make_float4(o[8], o[9], o[10], o[11]);
  op[3] = make_float4(o[12], o[13], o[14], o[15]);
}

// ---------------------------------------------------------------------------
extern "C" void kernel_launch(void* const* d_in, const int* in_sizes, int n_in,
                              void* d_out, int out_size, void* d_ws, size_t ws_size,
                              hipStream_t stream) {
  const float* xyz        = (const float*)d_in[0];
  const float* atom_xyz   = (const float*)d_in[1];
  const float* atom_types = (const float*)d_in[2];
  const float* Wt1 = (const float*)d_in[3];  const float* bt1 = (const float*)d_in[4];
  const float* Wt2 = (const float*)d_in[5];  const float* bt2 = (const float*)d_in[6];
  const float* Wt3 = (const float*)d_in[7];  const float* bt3 = (const float*)d_in[8];
  const float* W1  = (const float*)d_in[9];  const float* b1  = (const float*)d_in[10];
  const float* W2  = (const float*)d_in[11]; const float* b2  = (const float*)d_in[12];
  const float* W3  = (const float*)d_in[13]; const float* b3  = (const float*)d_in[14];
  const float* g1  = (const float*)d_in[15]; const float* be1 = (const float*)d_in[16];
  const float* g2  = (const float*)d_in[17]; const float* be2 = (const float*)d_in[18];
  float* out = (float*)d_out;

  float* ws = (float*)d_ws;
  // workspace layout (floats); all float4-aligned
  float4* atoms4   = (float4*)ws;                  // 8064 * 4   = 32256
  float*  t        = ws + 32256;                   // 8000 * 16  = 128000
  int*    knn_idx  = (int*)(ws + 160256);          // 480000
  float*  knn_invd = ws + 640256;                  // 480000
  float*  fx1      = ws + 1120256;                 // 480000
  float*  s2       = ws + 1600256;                 // 480000
  float*  gstats   = ws + 2080256;                 // 64

  hipMemsetAsync(gstats, 0, 64 * sizeof(float), stream);

  k1_prep<<<32, 256, 0, stream>>>(atom_xyz, atom_types, Wt1, bt1, Wt2, bt2,
                                  Wt3, bt3, atoms4, t);
  k2_knn<<<7500, 256, 0, stream>>>(xyz, atoms4, knn_idx, knn_invd);
  k3_stats1<<<1875, 256, 0, stream>>>(knn_idx, knn_invd, t, W1, b1, gstats);
  k4_main<<<1875, 256, 0, stream>>>(knn_idx, knn_invd, t, W1, b1, W2, b2,
                                    g1, be1, fx1, s2, gstats);
  k5_final<<<118, 256, 0, stream>>>(fx1, s2, gstats, W3, b3, g2, be2, out);
}

// Round 3
// 450.829 us; speedup vs baseline: 2.1549x; 2.1549x over previous
//
#include <hip/hip_runtime.h>

#define N_PTS   30000
#define M_ATOMS 8000
#define M_PAD   8064          // padded to multiple of 64
#define D       16
#define KNN     16
#define EPS     1e-5f
#define SLOPE   0.2f
#define BN_COUNT 480000.0f    // N_PTS * KNN

__device__ __forceinline__ float leaky(float x) { return x > 0.f ? x : SLOPE * x; }

// sortable key: monotone map float -> u32 (handles negatives; d2 can't be NaN here)
__device__ __forceinline__ unsigned fkey(float f) {
  unsigned u = __float_as_uint(f);
  return u ^ ((u & 0x80000000u) ? 0xFFFFFFFFu : 0x80000000u);
}

// ---------------------------------------------------------------------------
// K1: pack atoms as (x,y,z,|y|^2) float4 (padded with sentinel), and run the
// 3-layer transform_types MLP -> t[M,16]
// ---------------------------------------------------------------------------
#define LAYER(IN, OUT, W, B)                                        \
  _Pragma("unroll") for (int j = 0; j < 16; ++j) {                  \
    float acc = B[j];                                               \
    _Pragma("unroll") for (int i = 0; i < 16; ++i)                  \
      acc = fmaf(IN[i], W[i*16+j], acc);                            \
    OUT[j] = leaky(acc);                                            \
  }

__global__ void __launch_bounds__(256) k1_prep(
    const float* __restrict__ atom_xyz, const float* __restrict__ atom_types,
    const float* __restrict__ Wt1, const float* __restrict__ bt1,
    const float* __restrict__ Wt2, const float* __restrict__ bt2,
    const float* __restrict__ Wt3, const float* __restrict__ bt3,
    float4* __restrict__ atoms4, float* __restrict__ t_out) {
  __shared__ float w1[256], w2[256], w3[256], bb1[16], bb2[16], bb3[16];
  int tid = threadIdx.x;
  w1[tid] = Wt1[tid]; w2[tid] = Wt2[tid]; w3[tid] = Wt3[tid];
  if (tid < 16) { bb1[tid] = bt1[tid]; bb2[tid] = bt2[tid]; bb3[tid] = bt3[tid]; }
  __syncthreads();
  int m = blockIdx.x * 256 + tid;
  if (m >= M_PAD) return;
  if (m >= M_ATOMS) {                       // sentinel: d2 ~ 1e30, never selected
    atoms4[m] = make_float4(0.f, 0.f, 0.f, 1e30f);
    return;
  }
  float ax = atom_xyz[m*3+0], ay = atom_xyz[m*3+1], az = atom_xyz[m*3+2];
  atoms4[m] = make_float4(ax, ay, az, fmaf(ax,ax, fmaf(ay,ay, az*az)));

  float u[16], v[16];
  const float4* tp = (const float4*)(atom_types + (size_t)m*16);
  float4 q0 = tp[0], q1 = tp[1], q2 = tp[2], q3 = tp[3];
  u[0]=q0.x; u[1]=q0.y; u[2]=q0.z; u[3]=q0.w;
  u[4]=q1.x; u[5]=q1.y; u[6]=q1.z; u[7]=q1.w;
  u[8]=q2.x; u[9]=q2.y; u[10]=q2.z; u[11]=q2.w;
  u[12]=q3.x; u[13]=q3.y; u[14]=q3.z; u[15]=q3.w;

  LAYER(u, v, w1, bb1);
  LAYER(v, u, w2, bb2);
  LAYER(u, v, w3, bb3);

  float4* op = (float4*)(t_out + (size_t)m*16);
  op[0] = make_float4(v[0], v[1], v[2], v[3]);
  op[1] = make_float4(v[4], v[5], v[6], v[7]);
  op[2] = make_float4(v[8], v[9], v[10], v[11]);
  op[3] = make_float4(v[12], v[13], v[14], v[15]);
}

// ---------------------------------------------------------------------------
// K2 v2: exact 16-NN per point, throughput-oriented.
// Phase 1: per-lane branchless sorted top-4 of its 126 atoms (no cross-lane).
// Phase 2: 16 rounds of wave-wide u64 argmin over the 256 candidates
//          (key = sortable(d2) << 32 | idx  -> ties pick lower index, like top_k).
// Guard:   if any lane's 4th-best <= global 16th-best, that lane may have
//          discarded a true top-16 member (P ~ 0.6%): rerun proven v1 serial
//          algorithm for the whole wave.
// ---------------------------------------------------------------------------
__global__ void __launch_bounds__(256) k2_knn(
    const float* __restrict__ xyz, const float4* __restrict__ atoms4,
    int* __restrict__ knn_idx, float* __restrict__ knn_invd) {
  int lane = threadIdx.x & 63;
  int n = blockIdx.x * 4 + (threadIdx.x >> 6);
  if (n >= N_PTS) return;                    // wave-uniform

  float px = xyz[n*3+0], py = xyz[n*3+1], pz = xyz[n*3+2];
  float x2 = fmaf(px,px, fmaf(py,py, pz*pz));

  // ---- phase 1: per-lane sorted top-4 (ascending) ----
  float q0d=3.4e38f, q1d=3.4e38f, q2d=3.4e38f, q3d=3.4e38f;
  int   q0i=0, q1i=0, q2i=0, q3i=0;
#pragma unroll 2
  for (int s = 0; s < M_PAD/64; ++s) {
    int i = (s << 6) + lane;                 // consecutive lanes -> coalesced
    float4 a = atoms4[i];
    float dotp = fmaf(px,a.x, fmaf(py,a.y, pz*a.z));
    float d = (x2 + a.w) - 2.f*dotp;         // same expansion as reference
    // branchless sorted insert (strict <: ties keep earlier = lower idx)
    bool  c3 = d < q3d;
    float nd = c3 ? d : q3d;   int ni = c3 ? i  : q3i;
    bool  c2 = nd < q2d;
    q3d = c2 ? q2d : nd;       q3i = c2 ? q2i : ni;
    float m2 = c2 ? nd : q2d;  int i2 = c2 ? ni : q2i;
    bool  c1 = m2 < q1d;
    q2d = c1 ? q1d : m2;       q2i = c1 ? q1i : i2;
    float m1 = c1 ? m2 : q1d;  int i1 = c1 ? i2 : q1i;
    bool  c0 = m1 < q0d;
    q1d = c0 ? q0d : m1;       q1i = c0 ? q0i : i1;
    q0d = c0 ? m1 : q0d;       q0i = c0 ? i1 : q0i;
  }

  // ---- phase 2: merge 64x4 candidates, 16 x wave-argmin ----
  unsigned qmaxkey = fkey(q3d);              // lane's 4th-best (for safety check)
  unsigned long long e0 = ((unsigned long long)fkey(q0d) << 32) | (unsigned)q0i;
  unsigned long long e1 = ((unsigned long long)fkey(q1d) << 32) | (unsigned)q1i;
  unsigned long long e2 = ((unsigned long long)fkey(q2d) << 32) | (unsigned)q2i;
  unsigned long long e3 = ((unsigned long long)fkey(q3d) << 32) | (unsigned)q3i;

  unsigned long long res = 0, g = 0;
  for (int r = 0; r < KNN; ++r) {
    unsigned long long m01 = e0 < e1 ? e0 : e1;
    unsigned long long m23 = e2 < e3 ? e2 : e3;
    unsigned long long m   = m01 < m23 ? m01 : m23;
#pragma unroll
    for (int off = 1; off < 64; off <<= 1) {
      unsigned long long o = __shfl_xor(m, off, 64);
      m = o < m ? o : m;
    }
    if (lane == r) res = m;
    // owner clears its slot (atom indices unique across lanes -> unique key)
    e0 = (e0 == m) ? ~0ull : e0;
    e1 = (e1 == m) ? ~0ull : e1;
    e2 = (e2 == m) ? ~0ull : e2;
    e3 = (e3 == m) ? ~0ull : e3;
    g = m;
  }
  unsigned t16key = (unsigned)(g >> 32);     // 16th-best key (wave-uniform)
  bool risky = (qmaxkey <= t16key);          // lane may have discarded a top-16
  bool fb = (__ballot(risky) != 0ull);       // wave-uniform

  int outIdx = (int)(res & 0xFFFFFFFFull);

  if (fb) {
    // ---- fallback: proven v1 serial-insert algorithm (rare, ~0.6% of waves)
    float lv = 3.4e38f; int li = 0; float thresh = 3.4e38f;
    for (int base = 0; base < M_PAD; base += 64) {
      float4 a = atoms4[base + lane];
      float dotp = fmaf(px,a.x, fmaf(py,a.y, pz*a.z));
      float d2 = (x2 + a.w) - 2.f*dotp;
      unsigned long long mask = __ballot(d2 < thresh);
      while (mask) {
        int src = __ffsll(mask) - 1;
        mask &= mask - 1;
        float dc = __shfl(d2, src, 64);
        if (dc < thresh) {
          int mc = base + src;
          bool ins = (lane < KNN) && (dc < lv);
          float pv = __shfl_up(lv, 1, 64);
          int   pi = __shfl_up(li, 1, 64);
          int   pins = __shfl_up((int)ins, 1, 64);
          if (lane == 0) pins = 0;
          if (ins) {
            lv = pins ? pv : dc;
            li = pins ? pi : mc;
          }
          thresh = __shfl(lv, KNN-1, 64);
        }
      }
    }
    outIdx = li;
  }

  if (lane < KNN) {
    float4 a = atoms4[outIdx];
    float dx = px - a.x, dy = py - a.y, dz = pz - a.z;
    float dd = fmaf(dx,dx, fmaf(dy,dy, dz*dz));   // exact recompute (reference)
    knn_idx [n*KNN + lane] = outIdx;
    knn_invd[n*KNN + lane] = 1.f / dd;
  }
}

// ---------------------------------------------------------------------------
// conv1 (feat[17] @ W1[17,16] + b1) + leaky, weights in LDS
// ---------------------------------------------------------------------------
__device__ __forceinline__ void conv1_leaky(const float* tr, float iv,
                                            const float* w, const float* b,
                                            float* a) {
#pragma unroll
  for (int j = 0; j < 16; ++j) {
    float acc = fmaf(iv, w[256+j], b[j]);
#pragma unroll
    for (int i = 0; i < 16; ++i) acc = fmaf(tr[i], w[i*16+j], acc);
    a[j] = leaky(acc);
  }
}

__device__ __forceinline__ void load_trow(const float* __restrict__ t_in,
                                          int idx, float* tr) {
  const float4* tp = (const float4*)(t_in + (size_t)idx*16);
  float4 q0 = tp[0], q1 = tp[1], q2 = tp[2], q3 = tp[3];
  tr[0]=q0.x; tr[1]=q0.y; tr[2]=q0.z; tr[3]=q0.w;
  tr[4]=q1.x; tr[5]=q1.y; tr[6]=q1.z; tr[7]=q1.w;
  tr[8]=q2.x; tr[9]=q2.y; tr[10]=q2.z; tr[11]=q2.w;
  tr[12]=q3.x; tr[13]=q3.y; tr[14]=q3.z; tr[15]=q3.w;
}

// wave-reduce sum+sumsq of a[16] -> lane0 adds into LDS acc[32]
__device__ __forceinline__ void wave_stats_acc(const float* a, float* acc, int lane) {
#pragma unroll
  for (int j = 0; j < 16; ++j) {
    float s = a[j];
    float q = a[j] * a[j];
#pragma unroll
    for (int off = 32; off > 0; off >>= 1) {
      s += __shfl_down(s, off, 64);
      q += __shfl_down(q, off, 64);
    }
    if (lane == 0) { atomicAdd(&acc[j], s); atomicAdd(&acc[16+j], q); }
  }
}

// ---------------------------------------------------------------------------
// K3: BN1 statistics (sum / sumsq of a1 = leaky(conv1(feat)) per channel)
// gstats layout: [sum1(16) | sq1(16) | sum2(16) | sq2(16)]
// ---------------------------------------------------------------------------
__global__ void __launch_bounds__(256) k3_stats1(
    const int* __restrict__ knn_idx, const float* __restrict__ knn_invd,
    const float* __restrict__ t_in,
    const float* __restrict__ W1, const float* __restrict__ b1,
    float* __restrict__ gstats) {
  __shared__ float w[272], b[16], acc[32];
  int tid = threadIdx.x;
  int lane = tid & 63;
  w[tid] = W1[tid];
  if (tid < 16) w[256+tid] = W1[256+tid];
  if (tid < 16)  b[tid] = b1[tid];
  if (tid < 32)  acc[tid] = 0.f;
  __syncthreads();

  int g = blockIdx.x * 256 + tid;            // 1875*256 == 480000 exactly
  int idx = knn_idx[g];
  float iv = knn_invd[g];
  float tr[16], a[16];
  load_trow(t_in, idx, tr);
  conv1_leaky(tr, iv, w, b, a);
  wave_stats_acc(a, acc, lane);
  __syncthreads();
  if (tid < 32) atomicAdd(&gstats[tid], acc[tid]);
}

// ---------------------------------------------------------------------------
// K4: main pass. Recompute a1, apply BN1 -> h, fx1 = sum_k h (stored),
// a2 = leaky(h@W2+b2), s2 = sum_k a2 (stored), accumulate BN2 stats.
// Block = 16 points x 16 neighbors.
// ---------------------------------------------------------------------------
__global__ void __launch_bounds__(256) k4_main(
    const int* __restrict__ knn_idx, const float* __restrict__ knn_invd,
    const float* __restrict__ t_in,
    const float* __restrict__ W1, const float* __restrict__ b1,
    const float* __restrict__ W2, const float* __restrict__ b2,
    const float* __restrict__ g1, const float* __restrict__ be1,
    float* __restrict__ fx1_out, float* __restrict__ s2_out,
    float* __restrict__ gstats) {
  __shared__ float w1s[272], b1s[16], w2s[256], b2s[16];
  __shared__ float sc1[16], sh1[16];
  __shared__ float buf[16*16*17];            // [p][k][j] padded to 17
  __shared__ float acc[32];
  int tid = threadIdx.x;
  int lane = tid & 63;
  w1s[tid] = W1[tid];
  if (tid < 16) w1s[256+tid] = W1[256+tid];
  w2s[tid] = W2[tid];
  if (tid < 16) { b1s[tid] = b1[tid]; b2s[tid] = b2[tid]; }
  if (tid < 32) acc[tid] = 0.f;
  if (tid < 16) {
    float mean = gstats[tid]    * (1.f/BN_COUNT);
    float var  = gstats[16+tid] * (1.f/BN_COUNT) - mean*mean;
    float s = g1[tid] / sqrtf(var + EPS);
    sc1[tid] = s;
    sh1[tid] = be1[tid] - mean * s;
  }
  __syncthreads();

  int g = blockIdx.x * 256 + tid;
  int p = tid >> 4;                          // point slot within block
  int k = tid & 15;                          // neighbor slot
  int idx = knn_idx[g];
  float iv = knn_invd[g];
  float tr[16], a1[16], h[16], a2[16];
  load_trow(t_in, idx, tr);
  conv1_leaky(tr, iv, w1s, b1s, a1);
#pragma unroll
  for (int j = 0; j < 16; ++j) h[j] = fmaf(a1[j], sc1[j], sh1[j]);
#pragma unroll
  for (int j = 0; j < 16; ++j) {
    float accj = b2s[j];
#pragma unroll
    for (int i = 0; i < 16; ++i) accj = fmaf(h[i], w2s[i*16+j], accj);
    a2[j] = leaky(accj);
  }
  wave_stats_acc(a2, acc, lane);

  float* myrow = &buf[(p*16 + k)*17];
  // ---- reduce h over k -> fx1 ----
#pragma unroll
  for (int j = 0; j < 16; ++j) myrow[j] = h[j];
  __syncthreads();
  {
    int p2 = tid >> 4, j2 = tid & 15;
    float s = 0.f;
#pragma unroll
    for (int kk = 0; kk < 16; ++kk) s += buf[(p2*16+kk)*17 + j2];
    fx1_out[(size_t)blockIdx.x*256 + tid] = s;   // == fx1[n*16+j]
  }
  __syncthreads();
  // ---- reduce a2 over k -> s2 ----
#pragma unroll
  for (int j = 0; j < 16; ++j) myrow[j] = a2[j];
  __syncthreads();
  {
    int p2 = tid >> 4, j2 = tid & 15;
    float s = 0.f;
#pragma unroll
    for (int kk = 0; kk < 16; ++kk) s += buf[(p2*16+kk)*17 + j2];
    s2_out[(size_t)blockIdx.x*256 + tid] = s;
  }
  __syncthreads();
  if (tid < 32) atomicAdd(&gstats[32 + tid], acc[tid]);
}

// ---------------------------------------------------------------------------
// K5: fx2 = scale2*s2 + 16*shift2 ; out = [fx1, fx2] @ W3 + b3
// ---------------------------------------------------------------------------
__global__ void __launch_bounds__(256) k5_final(
    const float* __restrict__ fx1_in, const float* __restrict__ s2_in,
    const float* __restrict__ gstats,
    const float* __restrict__ W3, const float* __restrict__ b3,
    const float* __restrict__ g2, const float* __restrict__ be2,
    float* __restrict__ out) {
  __shared__ float w[512], bb[16], sc2[16], sh2[16];
  int tid = threadIdx.x;
  w[tid] = W3[tid]; w[256+tid] = W3[256+tid];
  if (tid < 16) {
    bb[tid] = b3[tid];
    float mean = gstats[32+tid] * (1.f/BN_COUNT);
    float var  = gstats[48+tid] * (1.f/BN_COUNT) - mean*mean;
    float s = g2[tid] / sqrtf(var + EPS);
    sc2[tid] = s;
    sh2[tid] = be2[tid] - mean * s;
  }
  __syncthreads();
  int n = blockIdx.x * 256 + tid;
  if (n >= N_PTS) return;

  float f1[16], f2[16];
  load_trow(fx1_in, n, f1);
  load_trow(s2_in,  n, f2);
#pragma unroll
  for (int i = 0; i < 16; ++i) f2[i] = fmaf(sc2[i], f2[i], 16.f * sh2[i]);

  float4* op = (float4*)(out + (size_t)n*16);
  float o[16];
#pragma unroll
  for (int j = 0; j < 16; ++j) {
    float accj = bb[j];
#pragma unroll
    for (int i = 0; i < 16; ++i) accj = fmaf(f1[i], w[i*16+j], accj);
#pragma unroll
    for (int i = 0; i < 16; ++i) accj = fmaf(f2[i], w[(16+i)*16+j], accj);
    o[j] = accj;
  }
  op[0] = make_float4(o[0], o[1], o[2], o[3]);
  op[1] = make_float4(o[4], o[5], o[6], o[7]);
  op[2] = make_float4(o[8], o[9], o[10], o[11]);
  op[3] = make_float4(o[12], o[13], o[14], o[15]);
}

// ---------------------------------------------------------------------------
extern "C" void kernel_launch(void* const* d_in, const int* in_sizes, int n_in,
                              void* d_out, int out_size, void* d_ws, size_t ws_size,
                              hipStream_t stream) {
  const float* xyz        = (const float*)d_in[0];
  const float* atom_xyz   = (const float*)d_in[1];
  const float* atom_types = (const float*)d_in[2];
  const float* Wt1 = (const float*)d_in[3];  const float* bt1 = (const float*)d_in[4];
  const float* Wt2 = (const float*)d_in[5];  const float* bt2 = (const float*)d_in[6];
  const float* Wt3 = (const float*)d_in[7];  const float* bt3 = (const float*)d_in[8];
  const float* W1  = (const float*)d_in[9];  const float* b1  = (const float*)d_in[10];
  const float* W2  = (const float*)d_in[11]; const float* b2  = (const float*)d_in[12];
  const float* W3  = (const float*)d_in[13]; const float* b3  = (const float*)d_in[14];
  const float* g1  = (const float*)d_in[15]; const float* be1 = (const float*)d_in[16];
  const float* g2  = (const float*)d_in[17]; const float* be2 = (const float*)d_in[18];
  float* out = (float*)d_out;

  float* ws = (float*)d_ws;
  float4* atoms4   = (float4*)ws;                  // 8064 * 4   = 32256
  float*  t        = ws + 32256;                   // 8000 * 16  = 128000
  int*    knn_idx  = (int*)(ws + 160256);          // 480000
  float*  knn_invd = ws + 640256;                  // 480000
  float*  fx1      = ws + 1120256;                 // 480000
  float*  s2       = ws + 1600256;                 // 480000
  float*  gstats   = ws + 2080256;                 // 64

  hipMemsetAsync(gstats, 0, 64 * sizeof(float), stream);

  k1_prep<<<32, 256, 0, stream>>>(atom_xyz, atom_types, Wt1, bt1, Wt2, bt2,
                                  Wt3, bt3, atoms4, t);
  k2_knn<<<7500, 256, 0, stream>>>(xyz, atoms4, knn_idx, knn_invd);
  k3_stats1<<<1875, 256, 0, stream>>>(knn_idx, knn_invd, t, W1, b1, gstats);
  k4_main<<<1875, 256, 0, stream>>>(knn_idx, knn_invd, t, W1, b1, W2, b2,
                                    g1, be1, fx1, s2, gstats);
  k5_final<<<118, 256, 0, stream>>>(fx1, s2, gstats, W3, b3, g2, be2, out);
}

// Round 4
// 369.792 us; speedup vs baseline: 2.6271x; 1.2191x over previous
//
#include <hip/hip_runtime.h>

#define N_PTS   30000
#define M_ATOMS 8000
#define M_PAD   8064          // padded to multiple of 64
#define D       16
#define KNN     16
#define EPS     1e-5f
#define SLOPE   0.2f
#define BN_COUNT 480000.0f    // N_PTS * KNN

__device__ __forceinline__ float leaky(float x) { return x > 0.f ? x : SLOPE * x; }

// sortable key: monotone map float -> u32
__device__ __forceinline__ unsigned fkey(float f) {
  unsigned u = __float_as_uint(f);
  return u ^ ((u & 0x80000000u) ? 0xFFFFFFFFu : 0x80000000u);
}

// wave-wide u64 pull-shuffle with precomputed byte address (lane*4)
__device__ __forceinline__ unsigned long long bperm64(int addr, unsigned long long v) {
  int lo = __builtin_amdgcn_ds_bpermute(addr, (int)(unsigned)(v & 0xFFFFFFFFull));
  int hi = __builtin_amdgcn_ds_bpermute(addr, (int)(unsigned)(v >> 32));
  return ((unsigned long long)(unsigned)hi << 32) | (unsigned)lo;
}

// ---------------------------------------------------------------------------
// K1: pack atoms as (x,y,z,|y|^2), transform_types MLP -> t[M,16], zero gstats
// ---------------------------------------------------------------------------
#define LAYER(IN, OUT, W, B)                                        \
  _Pragma("unroll") for (int j = 0; j < 16; ++j) {                  \
    float acc = B[j];                                               \
    _Pragma("unroll") for (int i = 0; i < 16; ++i)                  \
      acc = fmaf(IN[i], W[i*16+j], acc);                            \
    OUT[j] = leaky(acc);                                            \
  }

__global__ void __launch_bounds__(256) k1_prep(
    const float* __restrict__ atom_xyz, const float* __restrict__ atom_types,
    const float* __restrict__ Wt1, const float* __restrict__ bt1,
    const float* __restrict__ Wt2, const float* __restrict__ bt2,
    const float* __restrict__ Wt3, const float* __restrict__ bt3,
    float4* __restrict__ atoms4, float* __restrict__ t_out,
    float* __restrict__ gstats) {
  __shared__ float w1[256], w2[256], w3[256], bb1[16], bb2[16], bb3[16];
  int tid = threadIdx.x;
  if (blockIdx.x == 0 && tid < 64) gstats[tid] = 0.f;   // replaces memset launch
  w1[tid] = Wt1[tid]; w2[tid] = Wt2[tid]; w3[tid] = Wt3[tid];
  if (tid < 16) { bb1[tid] = bt1[tid]; bb2[tid] = bt2[tid]; bb3[tid] = bt3[tid]; }
  __syncthreads();
  int m = blockIdx.x * 256 + tid;
  if (m >= M_PAD) return;
  if (m >= M_ATOMS) {                       // sentinel: never selected
    atoms4[m] = make_float4(0.f, 0.f, 0.f, 1e30f);
    return;
  }
  float ax = atom_xyz[m*3+0], ay = atom_xyz[m*3+1], az = atom_xyz[m*3+2];
  atoms4[m] = make_float4(ax, ay, az, fmaf(ax,ax, fmaf(ay,ay, az*az)));

  float u[16], v[16];
  const float4* tp = (const float4*)(atom_types + (size_t)m*16);
  float4 q0 = tp[0], q1 = tp[1], q2 = tp[2], q3 = tp[3];
  u[0]=q0.x; u[1]=q0.y; u[2]=q0.z; u[3]=q0.w;
  u[4]=q1.x; u[5]=q1.y; u[6]=q1.z; u[7]=q1.w;
  u[8]=q2.x; u[9]=q2.y; u[10]=q2.z; u[11]=q2.w;
  u[12]=q3.x; u[13]=q3.y; u[14]=q3.z; u[15]=q3.w;

  LAYER(u, v, w1, bb1);
  LAYER(v, u, w2, bb2);
  LAYER(u, v, w3, bb3);

  float4* op = (float4*)(t_out + (size_t)m*16);
  op[0] = make_float4(v[0], v[1], v[2], v[3]);
  op[1] = make_float4(v[4], v[5], v[6], v[7]);
  op[2] = make_float4(v[8], v[9], v[10], v[11]);
  op[3] = make_float4(v[12], v[13], v[14], v[15]);
}

// ---------------------------------------------------------------------------
// K2 v3: exact 16-NN. Phase 1: per-lane sorted top-4, insert skipped via
// wave-uniform ballot guard (~85% of batches skip). Phase 2: 16 argmin pops
// with cursor (sorted list head) + precomputed bpermute addresses.
// Guard + serial fallback (proven v1) unchanged.
// ---------------------------------------------------------------------------
__global__ void __launch_bounds__(256) k2_knn(
    const float* __restrict__ xyz, const float4* __restrict__ atoms4,
    int* __restrict__ knn_idx, float* __restrict__ knn_invd) {
  int lane = threadIdx.x & 63;
  int n = blockIdx.x * 4 + (threadIdx.x >> 6);
  if (n >= N_PTS) return;                    // wave-uniform

  float px = xyz[n*3+0], py = xyz[n*3+1], pz = xyz[n*3+2];
  float x2 = fmaf(px,px, fmaf(py,py, pz*pz));

  // ---- phase 1: per-lane sorted top-4 (ascending), ballot-guarded insert ----
  float q0d=3.4e38f, q1d=3.4e38f, q2d=3.4e38f, q3d=3.4e38f;
  int   q0i=0, q1i=0, q2i=0, q3i=0;
  const float4* ap = atoms4 + lane;
#pragma unroll 4
  for (int s = 0; s < M_PAD/64; ++s) {
    float4 a = ap[s << 6];
    float dotp = fmaf(px,a.x, fmaf(py,a.y, pz*a.z));
    float d = (x2 + a.w) - 2.f*dotp;         // same expansion as reference
    if (__ballot(d < q3d)) {                 // wave-uniform skip (~85% skip)
      int i = (s << 6) + lane;
      // branchless sorted insert (strict <: ties keep earlier = lower idx)
      bool  c3 = d < q3d;
      float nd = c3 ? d : q3d;   int ni = c3 ? i  : q3i;
      bool  c2 = nd < q2d;
      q3d = c2 ? q2d : nd;       q3i = c2 ? q2i : ni;
      float m2 = c2 ? nd : q2d;  int i2 = c2 ? ni : q2i;
      bool  c1 = m2 < q1d;
      q2d = c1 ? q1d : m2;       q2i = c1 ? q1i : i2;
      float m1 = c1 ? m2 : q1d;  int i1 = c1 ? i2 : q1i;
      bool  c0 = m1 < q0d;
      q1d = c0 ? q0d : m1;       q1i = c0 ? q0i : i1;
      q0d = c0 ? m1 : q0d;       q0i = c0 ? i1 : q0i;
    }
  }

  // ---- phase 2: merge 64x4 candidates via 16 cursor-argmin pops ----
  unsigned qmaxkey = fkey(q3d);              // lane's 4th-best (safety check)
  unsigned long long e1 = ((unsigned long long)fkey(q1d) << 32) | (unsigned)q1i;
  unsigned long long e2 = ((unsigned long long)fkey(q2d) << 32) | (unsigned)q2i;
  unsigned long long e3 = ((unsigned long long)fkey(q3d) << 32) | (unsigned)q3i;
  unsigned long long cur = ((unsigned long long)fkey(q0d) << 32) | (unsigned)q0i;

  int ax1  = (lane ^ 1)  << 2, ax2  = (lane ^ 2)  << 2, ax4  = (lane ^ 4) << 2;
  int ax8  = (lane ^ 8)  << 2, ax16 = (lane ^ 16) << 2, ax32 = (lane ^ 32) << 2;

  unsigned long long res = 0, m = 0;
  for (int r = 0; r < KNN; ++r) {
    m = cur;
    { unsigned long long o = bperm64(ax1,  m); m = o < m ? o : m; }
    { unsigned long long o = bperm64(ax2,  m); m = o < m ? o : m; }
    { unsigned long long o = bperm64(ax4,  m); m = o < m ? o : m; }
    { unsigned long long o = bperm64(ax8,  m); m = o < m ? o : m; }
    { unsigned long long o = bperm64(ax16, m); m = o < m ? o : m; }
    { unsigned long long o = bperm64(ax32, m); m = o < m ? o : m; }
    if (lane == r) res = m;
    // owner pops its head (atom indices unique across lanes -> low32 unique)
    bool own = ((unsigned)cur == (unsigned)m);
    cur = own ? e1 : cur;
    e1  = own ? e2 : e1;
    e2  = own ? e3 : e2;
    e3  = own ? ~0ull : e3;
  }
  unsigned t16key = (unsigned)(m >> 32);     // 16th-best key (wave-uniform)
  bool risky = (qmaxkey <= t16key);          // lane may have discarded a top-16
  bool fb = (__ballot(risky) != 0ull);       // wave-uniform

  int outIdx = (int)(res & 0xFFFFFFFFull);

  if (fb) {
    // ---- fallback: proven serial-insert algorithm (rare, ~0.6% of waves)
    float lv = 3.4e38f; int li = 0; float thresh = 3.4e38f;
    for (int base = 0; base < M_PAD; base += 64) {
      float4 a = atoms4[base + lane];
      float dotp = fmaf(px,a.x, fmaf(py,a.y, pz*a.z));
      float d2 = (x2 + a.w) - 2.f*dotp;
      unsigned long long mask = __ballot(d2 < thresh);
      while (mask) {
        int src = __ffsll(mask) - 1;
        mask &= mask - 1;
        float dc = __shfl(d2, src, 64);
        if (dc < thresh) {
          int mc = base + src;
          bool ins = (lane < KNN) && (dc < lv);
          float pv = __shfl_up(lv, 1, 64);
          int   pi = __shfl_up(li, 1, 64);
          int   pins = __shfl_up((int)ins, 1, 64);
          if (lane == 0) pins = 0;
          if (ins) {
            lv = pins ? pv : dc;
            li = pins ? pi : mc;
          }
          thresh = __shfl(lv, KNN-1, 64);
        }
      }
    }
    outIdx = li;
  }

  if (lane < KNN) {
    float4 a = atoms4[outIdx];
    float dx = px - a.x, dy = py - a.y, dz = pz - a.z;
    float dd = fmaf(dx,dx, fmaf(dy,dy, dz*dz));   // exact recompute (reference)
    knn_idx [n*KNN + lane] = outIdx;
    knn_invd[n*KNN + lane] = 1.f / dd;
  }
}

// ---------------------------------------------------------------------------
// conv1 (feat[17] @ W1[17,16] + b1) + leaky, weights in LDS
// ---------------------------------------------------------------------------
__device__ __forceinline__ void conv1_leaky(const float* tr, float iv,
                                            const float* w, const float* b,
                                            float* a) {
#pragma unroll
  for (int j = 0; j < 16; ++j) {
    float acc = fmaf(iv, w[256+j], b[j]);
#pragma unroll
    for (int i = 0; i < 16; ++i) acc = fmaf(tr[i], w[i*16+j], acc);
    a[j] = leaky(acc);
  }
}

__device__ __forceinline__ void load_trow(const float* __restrict__ t_in,
                                          int idx, float* tr) {
  const float4* tp = (const float4*)(t_in + (size_t)idx*16);
  float4 q0 = tp[0], q1 = tp[1], q2 = tp[2], q3 = tp[3];
  tr[0]=q0.x; tr[1]=q0.y; tr[2]=q0.z; tr[3]=q0.w;
  tr[4]=q1.x; tr[5]=q1.y; tr[6]=q1.z; tr[7]=q1.w;
  tr[8]=q2.x; tr[9]=q2.y; tr[10]=q2.z; tr[11]=q2.w;
  tr[12]=q3.x; tr[13]=q3.y; tr[14]=q3.z; tr[15]=q3.w;
}

// ---------------------------------------------------------------------------
// K3: BN1 statistics via LDS transpose reduction (no bpermute storms)
// gstats layout: [sum1(16) | sq1(16) | sum2(16) | sq2(16)]
// ---------------------------------------------------------------------------
__global__ void __launch_bounds__(256, 4) k3_stats1(
    const int* __restrict__ knn_idx, const float* __restrict__ knn_invd,
    const float* __restrict__ t_in,
    const float* __restrict__ W1, const float* __restrict__ b1,
    float* __restrict__ gstats) {
  __shared__ float w[272], b[16];
  __shared__ float buf[16*16*17];            // [p][k][j] padded to 17
  int tid = threadIdx.x;
  w[tid] = W1[tid];
  if (tid < 16) w[256+tid] = W1[256+tid];
  if (tid < 16) b[tid] = b1[tid];
  __syncthreads();

  int g = blockIdx.x * 256 + tid;            // 1875*256 == 480000 exactly
  int p = tid >> 4, k = tid & 15;
  int idx = knn_idx[g];
  float iv = knn_invd[g];
  float tr[16], a[16];
  load_trow(t_in, idx, tr);
  conv1_leaky(tr, iv, w, b, a);

  float* myrow = &buf[(p*16 + k)*17];
  int p2 = tid >> 4, j2 = tid & 15;
  // sum pass
#pragma unroll
  for (int j = 0; j < 16; ++j) myrow[j] = a[j];
  __syncthreads();
  float s = 0.f;
#pragma unroll
  for (int kk = 0; kk < 16; ++kk) s += buf[(p2*16+kk)*17 + j2];
  __syncthreads();
  // sumsq pass
#pragma unroll
  for (int j = 0; j < 16; ++j) myrow[j] = a[j]*a[j];
  __syncthreads();
  float q = 0.f;
#pragma unroll
  for (int kk = 0; kk < 16; ++kk) q += buf[(p2*16+kk)*17 + j2];
  __syncthreads();
  // cross-p reduce (reuse buf: two disjoint regions)
  buf[p2*17 + j2] = s;
  buf[289 + p2*17 + j2] = q;
  __syncthreads();
  if (tid < 16) {
    float t1 = 0.f, t2 = 0.f;
#pragma unroll
    for (int pp = 0; pp < 16; ++pp) { t1 += buf[pp*17 + tid]; t2 += buf[289 + pp*17 + tid]; }
    atomicAdd(&gstats[tid],      t1);
    atomicAdd(&gstats[16 + tid], t2);
  }
}

// ---------------------------------------------------------------------------
// K4: recompute a1, BN1 -> h, fx1 = sum_k h; a2 = leaky(h@W2+b2),
// s2 = sum_k a2; BN2 stats via the same LDS transpose machinery.
// ---------------------------------------------------------------------------
__global__ void __launch_bounds__(256, 4) k4_main(
    const int* __restrict__ knn_idx, const float* __restrict__ knn_invd,
    const float* __restrict__ t_in,
    const float* __restrict__ W1, const float* __restrict__ b1,
    const float* __restrict__ W2, const float* __restrict__ b2,
    const float* __restrict__ g1, const float* __restrict__ be1,
    float* __restrict__ fx1_out, float* __restrict__ s2_out,
    float* __restrict__ gstats) {
  __shared__ float w1s[272], b1s[16], w2s[256], b2s[16];
  __shared__ float sc1[16], sh1[16];
  __shared__ float buf[16*16*17];            // [p][k][j] padded to 17
  int tid = threadIdx.x;
  w1s[tid] = W1[tid];
  if (tid < 16) w1s[256+tid] = W1[256+tid];
  w2s[tid] = W2[tid];
  if (tid < 16) { b1s[tid] = b1[tid]; b2s[tid] = b2[tid]; }
  if (tid < 16) {
    float mean = gstats[tid]    * (1.f/BN_COUNT);
    float var  = gstats[16+tid] * (1.f/BN_COUNT) - mean*mean;
    float sC = g1[tid] / sqrtf(var + EPS);
    sc1[tid] = sC;
    sh1[tid] = be1[tid] - mean * sC;
  }
  __syncthreads();

  int g = blockIdx.x * 256 + tid;
  int p = tid >> 4, k = tid & 15;
  int idx = knn_idx[g];
  float iv = knn_invd[g];
  float tr[16], h[16], a2[16];
  load_trow(t_in, idx, tr);
  conv1_leaky(tr, iv, w1s, b1s, h);          // h currently = a1
#pragma unroll
  for (int j = 0; j < 16; ++j) h[j] = fmaf(h[j], sc1[j], sh1[j]);   // in-place BN1
#pragma unroll
  for (int j = 0; j < 16; ++j) {
    float accj = b2s[j];
#pragma unroll
    for (int i = 0; i < 16; ++i) accj = fmaf(h[i], w2s[i*16+j], accj);
    a2[j] = leaky(accj);
  }

  float* myrow = &buf[(p*16 + k)*17];
  int p2 = tid >> 4, j2 = tid & 15;
  // ---- h pass -> fx1 ----
#pragma unroll
  for (int j = 0; j < 16; ++j) myrow[j] = h[j];
  __syncthreads();
  {
    float s = 0.f;
#pragma unroll
    for (int kk = 0; kk < 16; ++kk) s += buf[(p2*16+kk)*17 + j2];
    fx1_out[(size_t)blockIdx.x*256 + tid] = s;
  }
  __syncthreads();
  // ---- a2 pass -> s2 ----
#pragma unroll
  for (int j = 0; j < 16; ++j) myrow[j] = a2[j];
  __syncthreads();
  float s2v = 0.f;
#pragma unroll
  for (int kk = 0; kk < 16; ++kk) s2v += buf[(p2*16+kk)*17 + j2];
  s2_out[(size_t)blockIdx.x*256 + tid] = s2v;
  __syncthreads();
  // ---- a2^2 pass -> block sumsq ----
#pragma unroll
  for (int j = 0; j < 16; ++j) myrow[j] = a2[j]*a2[j];
  __syncthreads();
  float q2v = 0.f;
#pragma unroll
  for (int kk = 0; kk < 16; ++kk) q2v += buf[(p2*16+kk)*17 + j2];
  __syncthreads();
  buf[p2*17 + j2] = s2v;
  buf[289 + p2*17 + j2] = q2v;
  __syncthreads();
  if (tid < 16) {
    float t1 = 0.f, t2 = 0.f;
#pragma unroll
    for (int pp = 0; pp < 16; ++pp) { t1 += buf[pp*17 + tid]; t2 += buf[289 + pp*17 + tid]; }
    atomicAdd(&gstats[32 + tid], t1);
    atomicAdd(&gstats[48 + tid], t2);
  }
}

// ---------------------------------------------------------------------------
// K5: fx2 = scale2*s2 + 16*shift2 ; out = [fx1, fx2] @ W3 + b3
// ---------------------------------------------------------------------------
__global__ void __launch_bounds__(256) k5_final(
    const float* __restrict__ fx1_in, const float* __restrict__ s2_in,
    const float* __restrict__ gstats,
    const float* __restrict__ W3, const float* __restrict__ b3,
    const float* __restrict__ g2, const float* __restrict__ be2,
    float* __restrict__ out) {
  __shared__ float w[512], bb[16], sc2[16], sh2[16];
  int tid = threadIdx.x;
  w[tid] = W3[tid]; w[256+tid] = W3[256+tid];
  if (tid < 16) {
    bb[tid] = b3[tid];
    float mean = gstats[32+tid] * (1.f/BN_COUNT);
    float var  = gstats[48+tid] * (1.f/BN_COUNT) - mean*mean;
    float s = g2[tid] / sqrtf(var + EPS);
    sc2[tid] = s;
    sh2[tid] = be2[tid] - mean * s;
  }
  __syncthreads();
  int n = blockIdx.x * 256 + tid;
  if (n >= N_PTS) return;

  float f1[16], f2[16];
  load_trow(fx1_in, n, f1);
  load_trow(s2_in,  n, f2);
#pragma unroll
  for (int i = 0; i < 16; ++i) f2[i] = fmaf(sc2[i], f2[i], 16.f * sh2[i]);

  float4* op = (float4*)(out + (size_t)n*16);
  float o[16];
#pragma unroll
  for (int j = 0; j < 16; ++j) {
    float accj = bb[j];
#pragma unroll
    for (int i = 0; i < 16; ++i) accj = fmaf(f1[i], w[i*16+j], accj);
#pragma unroll
    for (int i = 0; i < 16; ++i) accj = fmaf(f2[i], w[(16+i)*16+j], accj);
    o[j] = accj;
  }
  op[0] = make_float4(o[0], o[1], o[2], o[3]);
  op[1] = make_float4(o[4], o[5], o[6], o[7]);
  op[2] = make_float4(o[8], o[9], o[10], o[11]);
  op[3] = make_float4(o[12], o[13], o[14], o[15]);
}

// ---------------------------------------------------------------------------
extern "C" void kernel_launch(void* const* d_in, const int* in_sizes, int n_in,
                              void* d_out, int out_size, void* d_ws, size_t ws_size,
                              hipStream_t stream) {
  const float* xyz        = (const float*)d_in[0];
  const float* atom_xyz   = (const float*)d_in[1];
  const float* atom_types = (const float*)d_in[2];
  const float* Wt1 = (const float*)d_in[3];  const float* bt1 = (const float*)d_in[4];
  const float* Wt2 = (const float*)d_in[5];  const float* bt2 = (const float*)d_in[6];
  const float* Wt3 = (const float*)d_in[7];  const float* bt3 = (const float*)d_in[8];
  const float* W1  = (const float*)d_in[9];  const float* b1  = (const float*)d_in[10];
  const float* W2  = (const float*)d_in[11]; const float* b2  = (const float*)d_in[12];
  const float* W3  = (const float*)d_in[13]; const float* b3  = (const float*)d_in[14];
  const float* g1  = (const float*)d_in[15]; const float* be1 = (const float*)d_in[16];
  const float* g2  = (const float*)d_in[17]; const float* be2 = (const float*)d_in[18];
  float* out = (float*)d_out;

  float* ws = (float*)d_ws;
  float4* atoms4   = (float4*)ws;                  // 8064 * 4   = 32256
  float*  t        = ws + 32256;                   // 8000 * 16  = 128000
  int*    knn_idx  = (int*)(ws + 160256);          // 480000
  float*  knn_invd = ws + 640256;                  // 480000
  float*  fx1      = ws + 1120256;                 // 480000
  float*  s2       = ws + 1600256;                 // 480000
  float*  gstats   = ws + 2080256;                 // 64

  k1_prep<<<32, 256, 0, stream>>>(atom_xyz, atom_types, Wt1, bt1, Wt2, bt2,
                                  Wt3, bt3, atoms4, t, gstats);
  k2_knn<<<7500, 256, 0, stream>>>(xyz, atoms4, knn_idx, knn_invd);
  k3_stats1<<<1875, 256, 0, stream>>>(knn_idx, knn_invd, t, W1, b1, gstats);
  k4_main<<<1875, 256, 0, stream>>>(knn_idx, knn_invd, t, W1, b1, W2, b2,
                                    g1, be1, fx1, s2, gstats);
  k5_final<<<118, 256, 0, stream>>>(fx1, s2, gstats, W3, b3, g2, be2, out);
}